// Round 11
// baseline (1494.894 us; speedup 1.0000x reference)
//
#include <hip/hip_runtime.h>
#include <hip/hip_bf16.h>
#include <cstdint>

// Qwen3-VL-MoE text experts: permute -> grouped GEMM (gate_up) -> SwiGLU ->
// grouped GEMM (down) -> unpermute+combine.  bf16 MFMA path.
// R11: R8 GEMM bodies (proven best).  dwn-weight transpose is FUSED into
// gemm1 as a wave-role split: waves 0-7 = R8 GEMM (65 barriers), waves 8-11
// transpose 16 dwn 64x64 tiles in a fixed 65-iteration barrier-matched loop
// (fill/drain paced by the GEMM's block barriers).  cvt_hidden + build_perm
// fused into the gup transpose kernel as block roles.

#define E_   32
#define H_   2048
#define D_   768
#define T_   4096
#define K_   8
#define M_   (T_ * K_)   // 32768 expanded rows
#define G_   (M_ / E_)   // 1024 rows per expert (balanced)
#define GU2  (2 * D_)    // 1536

typedef unsigned short u16;
typedef short bf16x8 __attribute__((ext_vector_type(8)));
typedef float f32x4 __attribute__((ext_vector_type(4)));
typedef unsigned short u16x2 __attribute__((ext_vector_type(2)));
typedef unsigned short u16x8 __attribute__((ext_vector_type(8)));

__device__ __forceinline__ u16 f2bf(float f) {          // RNE f32 -> bf16
  unsigned u = __float_as_uint(f);
  u += 0x7FFFu + ((u >> 16) & 1u);
  return (u16)(u >> 16);
}
__device__ __forceinline__ float bf2f(u16 v) {
  return __uint_as_float(((unsigned)v) << 16);
}

#define GLOAD16(g, l) __builtin_amdgcn_global_load_lds(                        \
    (const __attribute__((address_space(1))) void*)(g),                        \
    (__attribute__((address_space(3))) void*)(l), 16, 0, 0)

#define VM8()   asm volatile("s_waitcnt vmcnt(8)" ::: "memory")
#define VM4()   asm volatile("s_waitcnt vmcnt(4)" ::: "memory")
#define VM0()   asm volatile("s_waitcnt vmcnt(0)" ::: "memory")
#define LGKM0() asm volatile("s_waitcnt lgkmcnt(0)" ::: "memory")
#define SCHB()  __builtin_amdgcn_sched_barrier(0)
#define BAR()   __builtin_amdgcn_s_barrier()

// ------------------------------------------------------------ prep (fused) --
// Block roles: [0,24576) gup transpose (mode-1 remap), [24576,32768)
// cvt_hidden, [32768,32896) build_perm.
__global__ __launch_bounds__(256) void prep_fused(
    const float* __restrict__ hidden, u16* __restrict__ hid_bf,
    const float* __restrict__ gup_f, u16* __restrict__ gup_t,
    const int* __restrict__ ridx, int* __restrict__ perm,
    int* __restrict__ gcnt) {
  __shared__ u16 tl[64 * 72];
  __shared__ int lc[E_];
  __shared__ int lb[E_];
  const int bid = blockIdx.x;
  const int tid = threadIdx.x;
  if (bid < 24576) {
    // ---- gup transpose: in (E, H, 1536) f32 -> out (E, 1536i, H) bf16
    const int bx = bid % 24, by = (bid / 24) % 32, bz = bid / 768;
    const int c0 = bx * 64, r0 = by * 64;
    const float* ip = gup_f + ((size_t)bz * H_ + r0) * GU2 + c0;
    const int rr4 = tid >> 4;          // 0..15
    const int cc4 = (tid & 15) * 4;    // 0,4,..,60
#pragma unroll
    for (int p = 0; p < 4; ++p) {
      const int r = p * 16 + rr4;
      const float4 v = *(const float4*)&ip[(size_t)r * GU2 + cc4];
      tl[(cc4 + 0) * 72 + r] = f2bf(v.x);
      tl[(cc4 + 1) * 72 + r] = f2bf(v.y);
      tl[(cc4 + 2) * 72 + r] = f2bf(v.z);
      tl[(cc4 + 3) * 72 + r] = f2bf(v.w);
    }
    __syncthreads();
    const int rs = (tid & 7) * 8;
#pragma unroll
    for (int q = 0; q < 2; ++q) {
      const int c = q * 32 + (tid >> 3);
      const int gc = c0 + c;
      const int j = (gc < D_) ? gc : (gc - D_);
      const int rr = (j >> 4) * 32 + ((gc < D_) ? 0 : 16) + (j & 15);
      const u16x8 v = *(const u16x8*)&tl[c * 72 + rs];
      *(u16x8*)&gup_t[((size_t)bz * GU2 + rr) * H_ + r0 + rs] = v;
    }
  } else if (bid < 24576 + 8192) {
    // ---- cvt_hidden
    const int i = (bid - 24576) * 256 + tid;     // float4 groups
    const float4 v = ((const float4*)hidden)[i];
    u16x2 a; a.x = f2bf(v.x); a.y = f2bf(v.y);
    u16x2 b; b.x = f2bf(v.z); b.y = f2bf(v.w);
    *(u16x2*)&hid_bf[(size_t)i * 4]     = a;
    *(u16x2*)&hid_bf[(size_t)i * 4 + 2] = b;
  } else {
    // ---- build_perm (two-level atomic ranking; intra-group order arbitrary
    // but output values independent of it)
    const int blk = bid - 32768;
    if (tid < E_) lc[tid] = 0;
    __syncthreads();
    const int i = blk * 256 + tid;
    const int e = ridx[i];
    const int p = atomicAdd(&lc[e], 1);
    __syncthreads();
    if (tid < E_) lb[tid] = atomicAdd(&gcnt[tid], lc[tid]);
    __syncthreads();
    perm[e * G_ + lb[e] + p] = i;
  }
}

// --------------------------------------------------------------- GEMM1 -----
// 768 threads: waves 0-7 = R8 GEMM (256x256 tile, BK=32, 4-slot ring, depth-3,
// one barrier/tile, counted vmcnt, T1/T2/T5); waves 8-11 = dwn transpose,
// 16 tiles/block, 65-iteration barrier-matched loop.
__global__ __launch_bounds__(768, 1) void gemm1_swiglu(
    const u16* __restrict__ hid, const u16* __restrict__ gup,
    const int* __restrict__ perm, u16* __restrict__ act,
    const float* __restrict__ dwn_f, u16* __restrict__ dwn_t) {
  __shared__ u16 As[4][8192];   // 4 x 16 KiB
  __shared__ u16 Bs[4][8192];   // 4 x 16 KiB
  __shared__ u16 Ts[64 * 72];   // 9 KiB transpose tile (waves 8-11 only)
  const int NT = H_ / 32;       // 64 K-tiles -> 65 barriers total

  const int tid = threadIdx.x;
  const int w = tid >> 6;

  if (w < 8) {
    // ================= GEMM path (R8 verbatim; 512 threads) ===============
    const int nwg = 6 * 4 * E_;   // 768, %8==0
    const int wid = (blockIdx.x % 8) * (nwg / 8) + blockIdx.x / 8;
    const int e = wid / 24;
    const int mb = (wid / 6) % 4;
    const int nb = wid % 6;

    const int lane = tid & 63;
    const int wr = w >> 2, wc = w & 3;         // 2 x 4 wave grid

    const int srow = tid >> 2, schunk = tid & 3;
    const u16* pA[2]; const u16* pB[2];
#pragma unroll
    for (int q = 0; q < 2; ++q) {
      const int r = q * 128 + srow;
      const int cg = (schunk ^ ((r >> 1) & 3)) * 8;
      const int token = perm[e * G_ + mb * 256 + r] >> 3;
      pA[q] = hid + (size_t)token * H_ + cg;
      pB[q] = gup + ((size_t)e * GU2 + nb * 256 + r) * H_ + cg;
    }

    int aoff[8], boff[4];
    {
      const int l15 = lane & 15, hk = lane >> 4;
#pragma unroll
      for (int m = 0; m < 8; ++m) {
        const int rA = wr * 128 + m * 16 + l15;
        aoff[m] = rA * 32 + ((hk ^ ((rA >> 1) & 3)) * 8);
      }
#pragma unroll
      for (int n = 0; n < 4; ++n) {
        const int rB = wc * 64 + n * 16 + l15;
        boff[n] = rB * 32 + ((hk ^ ((rB >> 1) & 3)) * 8);
      }
    }

    f32x4 acc[8][4];
#pragma unroll
    for (int m = 0; m < 8; ++m)
#pragma unroll
      for (int n = 0; n < 4; ++n) acc[m][n] = (f32x4){0.f, 0.f, 0.f, 0.f};

    GLOAD16(pA[0], &As[0][tid * 8]);      GLOAD16(pA[1], &As[0][4096 + tid * 8]);
    GLOAD16(pB[0], &Bs[0][tid * 8]);      GLOAD16(pB[1], &Bs[0][4096 + tid * 8]);
    GLOAD16(pA[0] + 32, &As[1][tid * 8]); GLOAD16(pA[1] + 32, &As[1][4096 + tid * 8]);
    GLOAD16(pB[0] + 32, &Bs[1][tid * 8]); GLOAD16(pB[1] + 32, &Bs[1][4096 + tid * 8]);
    GLOAD16(pA[0] + 64, &As[2][tid * 8]); GLOAD16(pA[1] + 64, &As[2][4096 + tid * 8]);
    GLOAD16(pB[0] + 64, &Bs[2][tid * 8]); GLOAD16(pB[1] + 64, &Bs[2][4096 + tid * 8]);
    VM8(); BAR(); SCHB();                 // barrier #1

#pragma unroll 4
    for (int t = 0; t < NT; ++t) {        // 64 iterations, 1 barrier each
      const int slot = t & 3, ts = (t + 3) & 3;
      const bool st = (t + 3) < NT;
      const u16* Ab = As[slot]; const u16* Bb = Bs[slot];
      bf16x8 av[4], bv[4];
#pragma unroll
      for (int n = 0; n < 4; ++n) bv[n] = *(const bf16x8*)&Bb[boff[n]];
#pragma unroll
      for (int m = 0; m < 4; ++m) av[m] = *(const bf16x8*)&Ab[aoff[m]];
      if (st) {
        GLOAD16(pA[0] + (t + 3) * 32, &As[ts][tid * 8]);
        GLOAD16(pA[1] + (t + 3) * 32, &As[ts][4096 + tid * 8]);
      }
      SCHB(); LGKM0(); SCHB();
      __builtin_amdgcn_s_setprio(1);
#pragma unroll
      for (int m = 0; m < 4; ++m)
#pragma unroll
        for (int n = 0; n < 4; ++n)
          acc[m][n] = __builtin_amdgcn_mfma_f32_16x16x32_bf16(av[m], bv[n],
                                                              acc[m][n], 0, 0, 0);
      __builtin_amdgcn_s_setprio(0);
      SCHB();
#pragma unroll
      for (int m = 0; m < 4; ++m) av[m] = *(const bf16x8*)&Ab[aoff[m + 4]];
      if (st) {
        GLOAD16(pB[0] + (t + 3) * 32, &Bs[ts][tid * 8]);
        GLOAD16(pB[1] + (t + 3) * 32, &Bs[ts][4096 + tid * 8]);
      }
      SCHB(); LGKM0(); SCHB();
      __builtin_amdgcn_s_setprio(1);
#pragma unroll
      for (int m = 0; m < 4; ++m)
#pragma unroll
        for (int n = 0; n < 4; ++n)
          acc[m + 4][n] = __builtin_amdgcn_mfma_f32_16x16x32_bf16(av[m], bv[n],
                                                                  acc[m + 4][n], 0, 0, 0);
      __builtin_amdgcn_s_setprio(0);
      SCHB();
      if (t + 3 < NT)      { VM8(); }
      else if (t + 2 < NT) { VM4(); }
      else                 { VM0(); }
      BAR(); SCHB();
    }

    // epilogue: SwiGLU on paired (gate,up) fragments, store bf16 act
    const int lrow = (lane >> 4) * 4, lcol = lane & 15;
#pragma unroll
    for (int m = 0; m < 8; ++m)
#pragma unroll
      for (int p = 0; p < 2; ++p)
#pragma unroll
        for (int r = 0; r < 4; ++r) {
          const float g = acc[m][2 * p][r];
          const float u = acc[m][2 * p + 1][r];
          const float a_ = g / (1.f + __expf(-g)) * u;   // silu(g)*u
          const int row = mb * 256 + wr * 128 + m * 16 + lrow + r;
          const int dcol = (nb * 8 + wc * 2 + p) * 16 + lcol;
          act[((size_t)e * G_ + row) * D_ + dcol] = f2bf(a_);
        }
  } else {
    // ============== transpose path (waves 8-11; 256 threads) ==============
    // dwn (E, D, H) f32 -> dwn_t (E, H, D) bf16; 16 tiles of 64x64 per block.
    // Exactly 65 BAR()s to match the GEMM path.
    const int tid2 = tid - 512;
    const int rr4 = tid2 >> 4;         // 0..15
    const int cc4 = (tid2 & 15) * 4;   // 0,4,..,60
    const int rs  = (tid2 & 7) * 8;
    const int cdr = tid2 >> 3;         // 0..31
    for (int i = 0; i < NT + 1; ++i) { // 65 iterations
      if (i < 32) {
        const int j = blockIdx.x * 16 + (i >> 1);   // tile 0..12287
        const int cx = j & 31;                      // H-tile (32)
        const int ry = (j >> 5) % 12;               // D-tile (12)
        const int ez = j / 384;                     // expert (32)
        if ((i & 1) == 0) {
          // fill: read 64x64 f32, cvt, store col-major (pitch 72) in Ts
          const float* ip = dwn_f + ((size_t)(ez * D_ + ry * 64)) * H_ + cx * 64;
#pragma unroll
          for (int p = 0; p < 4; ++p) {
            const int r = p * 16 + rr4;
            const float4 v = *(const float4*)&ip[(size_t)r * H_ + cc4];
            Ts[(cc4 + 0) * 72 + r] = f2bf(v.x);
            Ts[(cc4 + 1) * 72 + r] = f2bf(v.y);
            Ts[(cc4 + 2) * 72 + r] = f2bf(v.z);
            Ts[(cc4 + 3) * 72 + r] = f2bf(v.w);
          }
        } else {
          // drain: 16B stores of transposed rows
#pragma unroll
          for (int q = 0; q < 2; ++q) {
            const int c = q * 32 + cdr;             // 0..63 (H within tile)
            const u16x8 v = *(const u16x8*)&Ts[c * 72 + rs];
            *(u16x8*)&dwn_t[((size_t)ez * H_ + cx * 64 + c) * D_ + ry * 64 + rs] = v;
          }
        }
      }
      LGKM0(); SCHB();
      BAR();
    }
  }
}

// --------------------------------------------------------------- GEMM2 -----
// R8 verbatim: 256x256 tile, BK=32, 4-slot ring, depth-3, one barrier/tile.
__global__ __launch_bounds__(512, 2) void gemm2_scatter(
    const u16* __restrict__ act, const u16* __restrict__ dwn,
    const int* __restrict__ perm, u16* __restrict__ expo) {
  __shared__ u16 As[4][8192];
  __shared__ u16 Bs[4][8192];
  const int NT = D_ / 32;       // 24 K-tiles

  const int nwg = 8 * 4 * E_;   // 1024, %8==0
  const int wid = (blockIdx.x % 8) * (nwg / 8) + blockIdx.x / 8;
  const int e = wid / 32;
  const int mb = (wid / 8) % 4;
  const int nb = wid % 8;

  const int tid = threadIdx.x;
  const int lane = tid & 63, w = tid >> 6;
  const int wr = w >> 2, wc = w & 3;

  const int srow = tid >> 2, schunk = tid & 3;
  const u16* pA[2]; const u16* pB[2];
#pragma unroll
  for (int q = 0; q < 2; ++q) {
    const int r = q * 128 + srow;
    const int cg = (schunk ^ ((r >> 1) & 3)) * 8;
    pA[q] = act + ((size_t)e * G_ + mb * 256 + r) * D_ + cg;
    pB[q] = dwn + ((size_t)e * H_ + nb * 256 + r) * D_ + cg;
  }

  int aoff[8], boff[4];
  {
    const int l15 = lane & 15, hk = lane >> 4;
#pragma unroll
    for (int m = 0; m < 8; ++m) {
      const int rA = wr * 128 + m * 16 + l15;
      aoff[m] = rA * 32 + ((hk ^ ((rA >> 1) & 3)) * 8);
    }
#pragma unroll
    for (int n = 0; n < 4; ++n) {
      const int rB = wc * 64 + n * 16 + l15;
      boff[n] = rB * 32 + ((hk ^ ((rB >> 1) & 3)) * 8);
    }
  }

  f32x4 acc[8][4];
#pragma unroll
  for (int m = 0; m < 8; ++m)
#pragma unroll
    for (int n = 0; n < 4; ++n) acc[m][n] = (f32x4){0.f, 0.f, 0.f, 0.f};

  GLOAD16(pA[0], &As[0][tid * 8]);      GLOAD16(pA[1], &As[0][4096 + tid * 8]);
  GLOAD16(pB[0], &Bs[0][tid * 8]);      GLOAD16(pB[1], &Bs[0][4096 + tid * 8]);
  GLOAD16(pA[0] + 32, &As[1][tid * 8]); GLOAD16(pA[1] + 32, &As[1][4096 + tid * 8]);
  GLOAD16(pB[0] + 32, &Bs[1][tid * 8]); GLOAD16(pB[1] + 32, &Bs[1][4096 + tid * 8]);
  GLOAD16(pA[0] + 64, &As[2][tid * 8]); GLOAD16(pA[1] + 64, &As[2][4096 + tid * 8]);
  GLOAD16(pB[0] + 64, &Bs[2][tid * 8]); GLOAD16(pB[1] + 64, &Bs[2][4096 + tid * 8]);
  VM8(); BAR(); SCHB();

#pragma unroll 4
  for (int t = 0; t < NT; ++t) {
    const int slot = t & 3, ts = (t + 3) & 3;
    const bool st = (t + 3) < NT;
    const u16* Ab = As[slot]; const u16* Bb = Bs[slot];
    bf16x8 av[4], bv[4];
#pragma unroll
    for (int n = 0; n < 4; ++n) bv[n] = *(const bf16x8*)&Bb[boff[n]];
#pragma unroll
    for (int m = 0; m < 4; ++m) av[m] = *(const bf16x8*)&Ab[aoff[m]];
    if (st) {
      GLOAD16(pA[0] + (t + 3) * 32, &As[ts][tid * 8]);
      GLOAD16(pA[1] + (t + 3) * 32, &As[ts][4096 + tid * 8]);
    }
    SCHB(); LGKM0(); SCHB();
    __builtin_amdgcn_s_setprio(1);
#pragma unroll
    for (int m = 0; m < 4; ++m)
#pragma unroll
      for (int n = 0; n < 4; ++n)
        acc[m][n] = __builtin_amdgcn_mfma_f32_16x16x32_bf16(av[m], bv[n],
                                                            acc[m][n], 0, 0, 0);
    __builtin_amdgcn_s_setprio(0);
    SCHB();
#pragma unroll
    for (int m = 0; m < 4; ++m) av[m] = *(const bf16x8*)&Ab[aoff[m + 4]];
    if (st) {
      GLOAD16(pB[0] + (t + 3) * 32, &Bs[ts][tid * 8]);
      GLOAD16(pB[1] + (t + 3) * 32, &Bs[ts][4096 + tid * 8]);
    }
    SCHB(); LGKM0(); SCHB();
    __builtin_amdgcn_s_setprio(1);
#pragma unroll
    for (int m = 0; m < 4; ++m)
#pragma unroll
      for (int n = 0; n < 4; ++n)
        acc[m + 4][n] = __builtin_amdgcn_mfma_f32_16x16x32_bf16(av[m], bv[n],
                                                                acc[m + 4][n], 0, 0, 0);
    __builtin_amdgcn_s_setprio(0);
    SCHB();
    if (t + 3 < NT)      { VM8(); }
    else if (t + 2 < NT) { VM4(); }
    else                 { VM0(); }
    BAR(); SCHB();
  }

  const int lrow = (lane >> 4) * 4, lcol = lane & 15;
#pragma unroll
  for (int m = 0; m < 8; ++m)
#pragma unroll
    for (int r = 0; r < 4; ++r) {
      const int dst = e * G_ + mb * 256 + wr * 128 + m * 16 + lrow + r;
      const int src = perm[dst];                 // expanded index t*K+k
      u16* orow = expo + (size_t)src * H_ + nb * 256 + wc * 64;
#pragma unroll
      for (int n = 0; n < 4; ++n)
        orow[n * 16 + lcol] = f2bf(acc[m][n][r]);
    }
}

// ------------------------------------------------------------- combine -----
__global__ __launch_bounds__(256) void combine(const u16* __restrict__ expo,
                                               const int* __restrict__ ridx,
                                               const float* __restrict__ rw,
                                               float* __restrict__ out) {
  __shared__ float pr[K_];
  const int t = blockIdx.x;
  if (threadIdx.x < K_)
    pr[threadIdx.x] = rw[t * E_ + ridx[t * K_ + threadIdx.x]];
  __syncthreads();
  const int h0 = threadIdx.x * 8;
  float r[8] = {0.f, 0.f, 0.f, 0.f, 0.f, 0.f, 0.f, 0.f};
#pragma unroll
  for (int k = 0; k < K_; ++k) {
    const float p = pr[k];
    const u16x8 v = *(const u16x8*)&expo[((size_t)(t * K_ + k)) * H_ + h0];
#pragma unroll
    for (int j = 0; j < 8; ++j) r[j] += p * bf2f(v[j]);
  }
  float4 o0 = {r[0], r[1], r[2], r[3]};
  float4 o1 = {r[4], r[5], r[6], r[7]};
  *(float4*)&out[(size_t)t * H_ + h0]     = o0;
  *(float4*)&out[(size_t)t * H_ + h0 + 4] = o1;
}

// -------------------------------------------------------------- launch -----
extern "C" void kernel_launch(void* const* d_in, const int* in_sizes, int n_in,
                              void* d_out, int out_size, void* d_ws, size_t ws_size,
                              hipStream_t stream) {
  const float* hidden = (const float*)d_in[0];   // (T, H) f32
  const float* rw     = (const float*)d_in[1];   // (T, E) f32
  const int*   ridx   = (const int*)d_in[2];     // (T, K) i32
  const float* gup_f  = (const float*)d_in[3];   // (E, H, 2D) f32
  const float* dwn_f  = (const float*)d_in[4];   // (E, D, H) f32
  float* out = (float*)d_out;                    // (T, H) f32

  char* ws = (char*)d_ws;
  size_t off = 0;
  auto alloc = [&](size_t bytes) -> void* {
    void* p = ws + off;
    off += (bytes + 255) & ~(size_t)255;
    return p;
  };
  u16*   hid_bf = (u16*)alloc((size_t)T_ * H_ * 2);        //  16.8 MB
  u16*   gup_t  = (u16*)alloc((size_t)E_ * GU2 * H_ * 2);  // 201.3 MB (E,1536i,H)
  u16*   dwn_t  = (u16*)alloc((size_t)E_ * H_ * D_ * 2);   // 100.7 MB (E,H,D)
  u16*   act    = (u16*)alloc((size_t)M_ * D_ * 2);        //  50.3 MB
  u16*   expo   = (u16*)alloc((size_t)M_ * H_ * 2);        // 134.2 MB
  int*   perm   = (int*)alloc((size_t)M_ * 4);
  int*   gcnt   = (int*)alloc((size_t)E_ * 4);
  if (off > ws_size) return;   // workspace too small -> clean fail

  hipMemsetAsync(gcnt, 0, E_ * sizeof(int), stream);
  prep_fused<<<24576 + 8192 + 128, 256, 0, stream>>>(hidden, hid_bf, gup_f,
                                                     gup_t, ridx, perm, gcnt);
  gemm1_swiglu<<<6 * 4 * E_, 768, 0, stream>>>(hid_bf, gup_t, perm, act,
                                               dwn_f, dwn_t);
  gemm2_scatter<<<8 * 4 * E_, 512, 0, stream>>>(act, dwn_t, perm, expo);
  combine<<<T_, 256, 0, stream>>>(expo, ridx, rw, out);
}

// Round 12
// 521.435 us; speedup vs baseline: 2.8669x; 2.8669x over previous
//
#include <hip/hip_runtime.h>
#include <hip/hip_bf16.h>
#include <cstdint>

// Qwen3-VL-MoE text experts: permute -> grouped GEMM (gate_up) -> SwiGLU ->
// grouped GEMM (down) -> unpermute+combine.  bf16 MFMA path.
// R12: consolidation.  GEMMs = R8 verbatim (best measured: 512 thr, (512,2),
// one barrier/K-tile, depth-3 4-slot ring, counted vmcnt, T1/T2/T5).
// prep_fused = block-role fusion of {gup transpose, cvt_hidden, build_perm}
// (independent blocks only -- R11's failed WAVE-role fusion is reverted).
// dwn transpose = standalone proven kernel.

#define E_   32
#define H_   2048
#define D_   768
#define T_   4096
#define K_   8
#define M_   (T_ * K_)   // 32768 expanded rows
#define G_   (M_ / E_)   // 1024 rows per expert (balanced)
#define GU2  (2 * D_)    // 1536

typedef unsigned short u16;
typedef short bf16x8 __attribute__((ext_vector_type(8)));
typedef float f32x4 __attribute__((ext_vector_type(4)));
typedef unsigned short u16x2 __attribute__((ext_vector_type(2)));
typedef unsigned short u16x8 __attribute__((ext_vector_type(8)));

__device__ __forceinline__ u16 f2bf(float f) {          // RNE f32 -> bf16
  unsigned u = __float_as_uint(f);
  u += 0x7FFFu + ((u >> 16) & 1u);
  return (u16)(u >> 16);
}
__device__ __forceinline__ float bf2f(u16 v) {
  return __uint_as_float(((unsigned)v) << 16);
}

#define GLOAD16(g, l) __builtin_amdgcn_global_load_lds(                        \
    (const __attribute__((address_space(1))) void*)(g),                        \
    (__attribute__((address_space(3))) void*)(l), 16, 0, 0)

#define VM8()   asm volatile("s_waitcnt vmcnt(8)" ::: "memory")
#define VM4()   asm volatile("s_waitcnt vmcnt(4)" ::: "memory")
#define VM0()   asm volatile("s_waitcnt vmcnt(0)" ::: "memory")
#define LGKM0() asm volatile("s_waitcnt lgkmcnt(0)" ::: "memory")
#define SCHB()  __builtin_amdgcn_sched_barrier(0)
#define BAR()   __builtin_amdgcn_s_barrier()

// ------------------------------------------------------------ prep (fused) --
// Block roles (independent blocks, no cross-role sync):
//   [0, 24576)        gup transpose (E,H,1536)f32 -> (E,1536i,H)bf16, mode-1
//   [24576, 32768)    cvt_hidden f32 -> bf16
//   [32768, 32896)    build_perm (two-level atomic ranking)
__global__ __launch_bounds__(256) void prep_fused(
    const float* __restrict__ hidden, u16* __restrict__ hid_bf,
    const float* __restrict__ gup_f, u16* __restrict__ gup_t,
    const int* __restrict__ ridx, int* __restrict__ perm,
    int* __restrict__ gcnt) {
  __shared__ u16 tl[64 * 72];
  __shared__ int lc[E_];
  __shared__ int lb[E_];
  const int bid = blockIdx.x;
  const int tid = threadIdx.x;
  if (bid < 24576) {
    const int bx = bid % 24, by = (bid / 24) % 32, bz = bid / 768;
    const int c0 = bx * 64, r0 = by * 64;
    const float* ip = gup_f + ((size_t)bz * H_ + r0) * GU2 + c0;
    const int rr4 = tid >> 4;          // 0..15
    const int cc4 = (tid & 15) * 4;    // 0,4,..,60
#pragma unroll
    for (int p = 0; p < 4; ++p) {
      const int r = p * 16 + rr4;
      const float4 v = *(const float4*)&ip[(size_t)r * GU2 + cc4];
      tl[(cc4 + 0) * 72 + r] = f2bf(v.x);
      tl[(cc4 + 1) * 72 + r] = f2bf(v.y);
      tl[(cc4 + 2) * 72 + r] = f2bf(v.z);
      tl[(cc4 + 3) * 72 + r] = f2bf(v.w);
    }
    __syncthreads();
    const int rs = (tid & 7) * 8;
#pragma unroll
    for (int q = 0; q < 2; ++q) {
      const int c = q * 32 + (tid >> 3);
      const int gc = c0 + c;
      const int j = (gc < D_) ? gc : (gc - D_);
      const int rr = (j >> 4) * 32 + ((gc < D_) ? 0 : 16) + (j & 15);
      const u16x8 v = *(const u16x8*)&tl[c * 72 + rs];
      *(u16x8*)&gup_t[((size_t)bz * GU2 + rr) * H_ + r0 + rs] = v;
    }
  } else if (bid < 24576 + 8192) {
    const int i = (bid - 24576) * 256 + tid;     // float4 groups
    const float4 v = ((const float4*)hidden)[i];
    u16x2 a; a.x = f2bf(v.x); a.y = f2bf(v.y);
    u16x2 b; b.x = f2bf(v.z); b.y = f2bf(v.w);
    *(u16x2*)&hid_bf[(size_t)i * 4]     = a;
    *(u16x2*)&hid_bf[(size_t)i * 4 + 2] = b;
  } else {
    // build_perm: intra-group order arbitrary; output values independent of it
    const int blk = bid - 32768;
    if (tid < E_) lc[tid] = 0;
    __syncthreads();
    const int i = blk * 256 + tid;
    const int e = ridx[i];
    const int p = atomicAdd(&lc[e], 1);
    __syncthreads();
    if (tid < E_) lb[tid] = atomicAdd(&gcnt[tid], lc[tid]);
    __syncthreads();
    perm[e * G_ + lb[e] + p] = i;
  }
}

// ----------------------------------------------------- dwn transpose -------
// (E, D, H) f32 -> (E, H, D) bf16.  Col-major LDS tile (pitch 72).
__global__ __launch_bounds__(256) void transpose_dwn(const float* __restrict__ in,
                                                     u16* __restrict__ out) {
  __shared__ u16 tl[64 * 72];        // tl[c*72 + r]
  const int b = blockIdx.z;
  const int c0 = blockIdx.x * 64, r0 = blockIdx.y * 64;
  const int tid = threadIdx.x;
  const float* ip = in + ((size_t)b * D_ + r0) * H_ + c0;
  const int rr4 = tid >> 4;          // 0..15
  const int cc4 = (tid & 15) * 4;    // 0,4,..,60
#pragma unroll
  for (int p = 0; p < 4; ++p) {
    const int r = p * 16 + rr4;
    const float4 v = *(const float4*)&ip[(size_t)r * H_ + cc4];
    tl[(cc4 + 0) * 72 + r] = f2bf(v.x);
    tl[(cc4 + 1) * 72 + r] = f2bf(v.y);
    tl[(cc4 + 2) * 72 + r] = f2bf(v.z);
    tl[(cc4 + 3) * 72 + r] = f2bf(v.w);
  }
  __syncthreads();
  const int rs = (tid & 7) * 8;      // 8-row strip start
#pragma unroll
  for (int q = 0; q < 2; ++q) {
    const int c = q * 32 + (tid >> 3);
    const u16x8 v = *(const u16x8*)&tl[c * 72 + rs];
    *(u16x8*)&out[((size_t)b * H_ + c0 + c) * D_ + r0 + rs] = v;
  }
}

// --------------------------------------------------------------- GEMM1 -----
// 256x256 tile, BK=32, 4-slot ring, depth-3 prefetch, 8 waves (2M x 4N).
// One barrier per K-tile (R8 verbatim).
__global__ __launch_bounds__(512, 2) void gemm1_swiglu(
    const u16* __restrict__ hid, const u16* __restrict__ gup,
    const int* __restrict__ perm, u16* __restrict__ act) {
  __shared__ u16 As[4][8192];   // 4 x 16 KiB
  __shared__ u16 Bs[4][8192];   // 4 x 16 KiB  (total 128 KiB)
  const int NT = H_ / 32;       // 64 K-tiles

  const int nwg = 6 * 4 * E_;   // 768, %8==0
  const int wid = (blockIdx.x % 8) * (nwg / 8) + blockIdx.x / 8;
  const int e = wid / 24;
  const int mb = (wid / 6) % 4;
  const int nb = wid % 6;

  const int tid = threadIdx.x;
  const int lane = tid & 63, w = tid >> 6;
  const int wr = w >> 2, wc = w & 3;           // 2 x 4 wave grid

  const int srow = tid >> 2, schunk = tid & 3;
  const u16* pA[2]; const u16* pB[2];
#pragma unroll
  for (int q = 0; q < 2; ++q) {
    const int r = q * 128 + srow;
    const int cg = (schunk ^ ((r >> 1) & 3)) * 8;
    const int token = perm[e * G_ + mb * 256 + r] >> 3;
    pA[q] = hid + (size_t)token * H_ + cg;
    pB[q] = gup + ((size_t)e * GU2 + nb * 256 + r) * H_ + cg;
  }

  int aoff[8], boff[4];
  {
    const int l15 = lane & 15, hk = lane >> 4;
#pragma unroll
    for (int m = 0; m < 8; ++m) {
      const int rA = wr * 128 + m * 16 + l15;
      aoff[m] = rA * 32 + ((hk ^ ((rA >> 1) & 3)) * 8);
    }
#pragma unroll
    for (int n = 0; n < 4; ++n) {
      const int rB = wc * 64 + n * 16 + l15;
      boff[n] = rB * 32 + ((hk ^ ((rB >> 1) & 3)) * 8);
    }
  }

  f32x4 acc[8][4];
#pragma unroll
  for (int m = 0; m < 8; ++m)
#pragma unroll
    for (int n = 0; n < 4; ++n) acc[m][n] = (f32x4){0.f, 0.f, 0.f, 0.f};

  GLOAD16(pA[0], &As[0][tid * 8]);      GLOAD16(pA[1], &As[0][4096 + tid * 8]);
  GLOAD16(pB[0], &Bs[0][tid * 8]);      GLOAD16(pB[1], &Bs[0][4096 + tid * 8]);
  GLOAD16(pA[0] + 32, &As[1][tid * 8]); GLOAD16(pA[1] + 32, &As[1][4096 + tid * 8]);
  GLOAD16(pB[0] + 32, &Bs[1][tid * 8]); GLOAD16(pB[1] + 32, &Bs[1][4096 + tid * 8]);
  GLOAD16(pA[0] + 64, &As[2][tid * 8]); GLOAD16(pA[1] + 64, &As[2][4096 + tid * 8]);
  GLOAD16(pB[0] + 64, &Bs[2][tid * 8]); GLOAD16(pB[1] + 64, &Bs[2][4096 + tid * 8]);
  VM8(); BAR(); SCHB();                 // tile 0 landed; tiles 1,2 in flight

#pragma unroll 4
  for (int t = 0; t < NT; ++t) {
    const int slot = t & 3, ts = (t + 3) & 3;
    const bool st = (t + 3) < NT;
    const u16* Ab = As[slot]; const u16* Bb = Bs[slot];
    bf16x8 av[4], bv[4];
#pragma unroll
    for (int n = 0; n < 4; ++n) bv[n] = *(const bf16x8*)&Bb[boff[n]];
#pragma unroll
    for (int m = 0; m < 4; ++m) av[m] = *(const bf16x8*)&Ab[aoff[m]];
    if (st) {
      GLOAD16(pA[0] + (t + 3) * 32, &As[ts][tid * 8]);
      GLOAD16(pA[1] + (t + 3) * 32, &As[ts][4096 + tid * 8]);
    }
    SCHB(); LGKM0(); SCHB();
    __builtin_amdgcn_s_setprio(1);
#pragma unroll
    for (int m = 0; m < 4; ++m)
#pragma unroll
      for (int n = 0; n < 4; ++n)
        acc[m][n] = __builtin_amdgcn_mfma_f32_16x16x32_bf16(av[m], bv[n],
                                                            acc[m][n], 0, 0, 0);
    __builtin_amdgcn_s_setprio(0);
    SCHB();
#pragma unroll
    for (int m = 0; m < 4; ++m) av[m] = *(const bf16x8*)&Ab[aoff[m + 4]];
    if (st) {
      GLOAD16(pB[0] + (t + 3) * 32, &Bs[ts][tid * 8]);
      GLOAD16(pB[1] + (t + 3) * 32, &Bs[ts][4096 + tid * 8]);
    }
    SCHB(); LGKM0(); SCHB();
    __builtin_amdgcn_s_setprio(1);
#pragma unroll
    for (int m = 0; m < 4; ++m)
#pragma unroll
      for (int n = 0; n < 4; ++n)
        acc[m + 4][n] = __builtin_amdgcn_mfma_f32_16x16x32_bf16(av[m], bv[n],
                                                                acc[m + 4][n], 0, 0, 0);
    __builtin_amdgcn_s_setprio(0);
    SCHB();
    if (t + 3 < NT)      { VM8(); }
    else if (t + 2 < NT) { VM4(); }
    else                 { VM0(); }
    BAR(); SCHB();
  }

  const int lrow = (lane >> 4) * 4, lcol = lane & 15;
#pragma unroll
  for (int m = 0; m < 8; ++m)
#pragma unroll
    for (int p = 0; p < 2; ++p)
#pragma unroll
      for (int r = 0; r < 4; ++r) {
        const float g = acc[m][2 * p][r];
        const float u = acc[m][2 * p + 1][r];
        const float a_ = g / (1.f + __expf(-g)) * u;     // silu(g)*u
        const int row = mb * 256 + wr * 128 + m * 16 + lrow + r;
        const int dcol = (nb * 8 + wc * 2 + p) * 16 + lcol;
        act[((size_t)e * G_ + row) * D_ + dcol] = f2bf(a_);
      }
}

// --------------------------------------------------------------- GEMM2 -----
// Same structure, K=768; one barrier per K-tile; scatter epilogue (R8).
__global__ __launch_bounds__(512, 2) void gemm2_scatter(
    const u16* __restrict__ act, const u16* __restrict__ dwn,
    const int* __restrict__ perm, u16* __restrict__ expo) {
  __shared__ u16 As[4][8192];
  __shared__ u16 Bs[4][8192];
  const int NT = D_ / 32;       // 24 K-tiles

  const int nwg = 8 * 4 * E_;   // 1024, %8==0
  const int wid = (blockIdx.x % 8) * (nwg / 8) + blockIdx.x / 8;
  const int e = wid / 32;
  const int mb = (wid / 8) % 4;
  const int nb = wid % 8;

  const int tid = threadIdx.x;
  const int lane = tid & 63, w = tid >> 6;
  const int wr = w >> 2, wc = w & 3;

  const int srow = tid >> 2, schunk = tid & 3;
  const u16* pA[2]; const u16* pB[2];
#pragma unroll
  for (int q = 0; q < 2; ++q) {
    const int r = q * 128 + srow;
    const int cg = (schunk ^ ((r >> 1) & 3)) * 8;
    pA[q] = act + ((size_t)e * G_ + mb * 256 + r) * D_ + cg;
    pB[q] = dwn + ((size_t)e * H_ + nb * 256 + r) * D_ + cg;
  }

  int aoff[8], boff[4];
  {
    const int l15 = lane & 15, hk = lane >> 4;
#pragma unroll
    for (int m = 0; m < 8; ++m) {
      const int rA = wr * 128 + m * 16 + l15;
      aoff[m] = rA * 32 + ((hk ^ ((rA >> 1) & 3)) * 8);
    }
#pragma unroll
    for (int n = 0; n < 4; ++n) {
      const int rB = wc * 64 + n * 16 + l15;
      boff[n] = rB * 32 + ((hk ^ ((rB >> 1) & 3)) * 8);
    }
  }

  f32x4 acc[8][4];
#pragma unroll
  for (int m = 0; m < 8; ++m)
#pragma unroll
    for (int n = 0; n < 4; ++n) acc[m][n] = (f32x4){0.f, 0.f, 0.f, 0.f};

  GLOAD16(pA[0], &As[0][tid * 8]);      GLOAD16(pA[1], &As[0][4096 + tid * 8]);
  GLOAD16(pB[0], &Bs[0][tid * 8]);      GLOAD16(pB[1], &Bs[0][4096 + tid * 8]);
  GLOAD16(pA[0] + 32, &As[1][tid * 8]); GLOAD16(pA[1] + 32, &As[1][4096 + tid * 8]);
  GLOAD16(pB[0] + 32, &Bs[1][tid * 8]); GLOAD16(pB[1] + 32, &Bs[1][4096 + tid * 8]);
  GLOAD16(pA[0] + 64, &As[2][tid * 8]); GLOAD16(pA[1] + 64, &As[2][4096 + tid * 8]);
  GLOAD16(pB[0] + 64, &Bs[2][tid * 8]); GLOAD16(pB[1] + 64, &Bs[2][4096 + tid * 8]);
  VM8(); BAR(); SCHB();

#pragma unroll 4
  for (int t = 0; t < NT; ++t) {
    const int slot = t & 3, ts = (t + 3) & 3;
    const bool st = (t + 3) < NT;
    const u16* Ab = As[slot]; const u16* Bb = Bs[slot];
    bf16x8 av[4], bv[4];
#pragma unroll
    for (int n = 0; n < 4; ++n) bv[n] = *(const bf16x8*)&Bb[boff[n]];
#pragma unroll
    for (int m = 0; m < 4; ++m) av[m] = *(const bf16x8*)&Ab[aoff[m]];
    if (st) {
      GLOAD16(pA[0] + (t + 3) * 32, &As[ts][tid * 8]);
      GLOAD16(pA[1] + (t + 3) * 32, &As[ts][4096 + tid * 8]);
    }
    SCHB(); LGKM0(); SCHB();
    __builtin_amdgcn_s_setprio(1);
#pragma unroll
    for (int m = 0; m < 4; ++m)
#pragma unroll
      for (int n = 0; n < 4; ++n)
        acc[m][n] = __builtin_amdgcn_mfma_f32_16x16x32_bf16(av[m], bv[n],
                                                            acc[m][n], 0, 0, 0);
    __builtin_amdgcn_s_setprio(0);
    SCHB();
#pragma unroll
    for (int m = 0; m < 4; ++m) av[m] = *(const bf16x8*)&Ab[aoff[m + 4]];
    if (st) {
      GLOAD16(pB[0] + (t + 3) * 32, &Bs[ts][tid * 8]);
      GLOAD16(pB[1] + (t + 3) * 32, &Bs[ts][4096 + tid * 8]);
    }
    SCHB(); LGKM0(); SCHB();
    __builtin_amdgcn_s_setprio(1);
#pragma unroll
    for (int m = 0; m < 4; ++m)
#pragma unroll
      for (int n = 0; n < 4; ++n)
        acc[m + 4][n] = __builtin_amdgcn_mfma_f32_16x16x32_bf16(av[m], bv[n],
                                                                acc[m + 4][n], 0, 0, 0);
    __builtin_amdgcn_s_setprio(0);
    SCHB();
    if (t + 3 < NT)      { VM8(); }
    else if (t + 2 < NT) { VM4(); }
    else                 { VM0(); }
    BAR(); SCHB();
  }

  const int lrow = (lane >> 4) * 4, lcol = lane & 15;
#pragma unroll
  for (int m = 0; m < 8; ++m)
#pragma unroll
    for (int r = 0; r < 4; ++r) {
      const int dst = e * G_ + mb * 256 + wr * 128 + m * 16 + lrow + r;
      const int src = perm[dst];                 // expanded index t*K+k
      u16* orow = expo + (size_t)src * H_ + nb * 256 + wc * 64;
#pragma unroll
      for (int n = 0; n < 4; ++n)
        orow[n * 16 + lcol] = f2bf(acc[m][n][r]);
    }
}

// ------------------------------------------------------------- combine -----
__global__ __launch_bounds__(256) void combine(const u16* __restrict__ expo,
                                               const int* __restrict__ ridx,
                                               const float* __restrict__ rw,
                                               float* __restrict__ out) {
  __shared__ float pr[K_];
  const int t = blockIdx.x;
  if (threadIdx.x < K_)
    pr[threadIdx.x] = rw[t * E_ + ridx[t * K_ + threadIdx.x]];
  __syncthreads();
  const int h0 = threadIdx.x * 8;
  float r[8] = {0.f, 0.f, 0.f, 0.f, 0.f, 0.f, 0.f, 0.f};
#pragma unroll
  for (int k = 0; k < K_; ++k) {
    const float p = pr[k];
    const u16x8 v = *(const u16x8*)&expo[((size_t)(t * K_ + k)) * H_ + h0];
#pragma unroll
    for (int j = 0; j < 8; ++j) r[j] += p * bf2f(v[j]);
  }
  float4 o0 = {r[0], r[1], r[2], r[3]};
  float4 o1 = {r[4], r[5], r[6], r[7]};
  *(float4*)&out[(size_t)t * H_ + h0]     = o0;
  *(float4*)&out[(size_t)t * H_ + h0 + 4] = o1;
}

// -------------------------------------------------------------- launch -----
extern "C" void kernel_launch(void* const* d_in, const int* in_sizes, int n_in,
                              void* d_out, int out_size, void* d_ws, size_t ws_size,
                              hipStream_t stream) {
  const float* hidden = (const float*)d_in[0];   // (T, H) f32
  const float* rw     = (const float*)d_in[1];   // (T, E) f32
  const int*   ridx   = (const int*)d_in[2];     // (T, K) i32
  const float* gup_f  = (const float*)d_in[3];   // (E, H, 2D) f32
  const float* dwn_f  = (const float*)d_in[4];   // (E, D, H) f32
  float* out = (float*)d_out;                    // (T, H) f32

  char* ws = (char*)d_ws;
  size_t off = 0;
  auto alloc = [&](size_t bytes) -> void* {
    void* p = ws + off;
    off += (bytes + 255) & ~(size_t)255;
    return p;
  };
  u16*   hid_bf = (u16*)alloc((size_t)T_ * H_ * 2);        //  16.8 MB
  u16*   gup_t  = (u16*)alloc((size_t)E_ * GU2 * H_ * 2);  // 201.3 MB (E,1536i,H)
  u16*   dwn_t  = (u16*)alloc((size_t)E_ * H_ * D_ * 2);   // 100.7 MB (E,H,D)
  u16*   act    = (u16*)alloc((size_t)M_ * D_ * 2);        //  50.3 MB
  u16*   expo   = (u16*)alloc((size_t)M_ * H_ * 2);        // 134.2 MB
  int*   perm   = (int*)alloc((size_t)M_ * 4);
  int*   gcnt   = (int*)alloc((size_t)E_ * 4);
  if (off > ws_size) return;   // workspace too small -> clean fail

  hipMemsetAsync(gcnt, 0, E_ * sizeof(int), stream);
  prep_fused<<<24576 + 8192 + 128, 256, 0, stream>>>(hidden, hid_bf, gup_f,
                                                     gup_t, ridx, perm, gcnt);
  transpose_dwn<<<dim3(H_ / 64, D_ / 64, E_), 256, 0, stream>>>(dwn_f, dwn_t);
  gemm1_swiglu<<<6 * 4 * E_, 512, 0, stream>>>(hid_bf, gup_t, perm, act);
  gemm2_scatter<<<8 * 4 * E_, 512, 0, stream>>>(act, dwn_t, perm, expo);
  combine<<<T_, 256, 0, stream>>>(expo, ridx, rw, out);
}